// Round 6
// baseline (212.219 us; speedup 1.0000x reference)
//
#include <hip/hip_runtime.h>
#include <hip/hip_bf16.h>
#include <math.h>

// BERT-CRF forward NLL on MI355X — chunked associative-scan formulation.
// p_t = D_t E^T p_{t-1}  (D_t = diag(exp(feat_t)), E = exp(trans)).
// Phase 1: for each (item, chunk of 64 steps), compute the 32x32 product
//   M_c = prod_t (D_t E^T) via MFMA (2x mfma_f32_32x32x16_bf16 per step),
//   with per-step 2^-k renorm folded into the A operand (k accumulated).
//   8192 independent waves -> ~4 waves/SIMD -> latency hidden.
// Phase 2: per item, p = M_7 ... M_0 p_0 (8 matvecs), forward score,
//   gold score gather tail (from R4), atomicAdd.

constexpr int NTAG = 32;
constexpr int TSTART = 30;
constexpr int TSTOP = 31;
constexpr int NB = 1024;
constexpr int NS = 512;
constexpr int CHUNK = 64;
constexpr int NCHUNK = 8;

constexpr float LOG2E = 1.44269504088896340736f;
constexpr float LN2   = 0.69314718055994530942f;

typedef short  bf16x8 __attribute__((ext_vector_type(8)));
typedef float  f32x16 __attribute__((ext_vector_type(16)));

union PKU { bf16x8 v; unsigned u[4]; };

__device__ __forceinline__ float fexp2(float x) {
#if __has_builtin(__builtin_amdgcn_exp2f)
    return __builtin_amdgcn_exp2f(x);
#else
    return exp2f(x);
#endif
}
__device__ __forceinline__ unsigned pk2(float a, float b) {
    union { __hip_bfloat162 h; unsigned u; } cv;
    cv.h = __float22bfloat162_rn(make_float2(a, b));
    return cv.u;
}

// ---------------- Phase 1: per-(item,chunk) matrix products ----------------
__global__ __launch_bounds__(256, 4)
void crf_phase1(const float* __restrict__ feats,
                const int*   __restrict__ lengths,
                const float* __restrict__ trans,
                unsigned short* __restrict__ wsM,   // [item][chunk][s:16][lane:64]
                int*            __restrict__ wsK)   // [item][chunk]
{
    const int lane  = threadIdx.x & 63;
    const int wid   = threadIdx.x >> 6;
    const int gid   = blockIdx.x * 4 + wid;
    const int item  = gid >> 3;
    const int chunk = gid & 7;
    const int m     = lane & 31;   // A row / C col index
    const int h     = lane >> 5;

    // Static A fragments: E^T[m][k] = exp(trans[k][m]), k = g*16 + h*8 + e
    float Efrag[2][8];
    #pragma unroll
    for (int g = 0; g < 2; ++g)
        #pragma unroll
        for (int e = 0; e < 8; ++e) {
            int k = g * 16 + h * 8 + e;
            Efrag[g][e] = fexp2(trans[k * 32 + m] * LOG2E);
        }

    const int len  = lengths[item];
    const int base = chunk * CHUNK;               // steps t = base+1 .. base+cnt
    int cnt = len - 1 - base;
    int cmax = min(CHUNK, NS - 1 - base);
    cnt = max(0, min(cnt, cmax));

    unsigned short* outM = wsM + ((size_t)(item * NCHUNK + chunk) << 10);

    if (cnt == 0) {
        // M = identity, creg = 0
        #pragma unroll
        for (int s = 0; s < 16; ++s) {
            int mm = (s & 3) + 8 * (s >> 2) + 4 * h;
            outM[s * 64 + lane] = (mm == m) ? (unsigned short)0x3F80 : (unsigned short)0;
        }
        if (lane == 0) wsK[item * NCHUNK + chunk] = 0;
        return;
    }

    // Seed B = I (B_g element e: k = g*16 + h*8 + e, col n = m)
    PKU B0, B1;
    #pragma unroll
    for (int r = 0; r < 4; ++r) {
        int k0 = h * 8 + 2 * r;
        B0.u[r] = ((k0 == m) ? 0x3F80u : 0u) | (((k0 + 1 == m) ? 0x3F80u : 0u) << 16);
        int k2 = 16 + h * 8 + 2 * r;
        B1.u[r] = ((k2 == m) ? 0x3F80u : 0u) | (((k2 + 1 == m) ? 0x3F80u : 0u) << 16);
    }

    const float* fb = feats + (size_t)item * NS * NTAG;

    // feat prefetch ring (depth 4); step i uses t = base+1+i, tag = m
    float pfr[4];
    #pragma unroll
    for (int d = 0; d < 4; ++d) {
        int i = (d < cnt) ? d : 0;
        pfr[d] = fb[(size_t)(base + 1 + i) * NTAG + m];
    }

    const bool hi = (h == 1);
    int creg = 0, knext = 0;
    f32x16 C;

    for (int i = 0; i < cnt; ++i) {
        float fv = pfr[i & 3];
        int ip = i + 4;
        if (ip < cnt) pfr[i & 3] = fb[(size_t)(base + 1 + ip) * NTAG + m];

        creg += knext;
        float kf = (float)knext;
        float ex = fexp2(fmaf(fv, LOG2E, -kf));   // exp(feat)*2^-k, per row m

        PKU A0, A1;
        #pragma unroll
        for (int r = 0; r < 4; ++r) {
            A0.u[r] = pk2(ex * Efrag[0][2 * r], ex * Efrag[0][2 * r + 1]);
            A1.u[r] = pk2(ex * Efrag[1][2 * r], ex * Efrag[1][2 * r + 1]);
        }

        f32x16 z;
        #pragma unroll
        for (int e = 0; e < 16; ++e) z[e] = 0.0f;
        C = __builtin_amdgcn_mfma_f32_32x32x16_bf16(A0.v, B0.v, z, 0, 0, 0);
        C = __builtin_amdgcn_mfma_f32_32x32x16_bf16(A1.v, B1.v, C, 0, 0, 0);

        // renorm exponent for next step (C[0] lane0 = M[0][0] > 0)
        int bits = __builtin_amdgcn_readfirstlane(__float_as_int(C[0]));
        int e_ = min(max((bits >> 23) & 0xFF, 1), 254);
        knext = e_ - 127;

        // C -> B relayout (C: col n=m, row = (r&3)+8*(r>>2)+4*h)
        unsigned P01 = pk2(C[0],  C[1]);   // rows (0,1)L/(4,5)H
        unsigned P23 = pk2(C[2],  C[3]);   // (2,3)/(6,7)
        unsigned P45 = pk2(C[4],  C[5]);   // (8,9)/(12,13)
        unsigned P67 = pk2(C[6],  C[7]);   // (10,11)/(14,15)
        unsigned Q01 = pk2(C[8],  C[9]);   // (16,17)/(20,21)
        unsigned Q23 = pk2(C[10], C[11]);  // (18,19)/(22,23)
        unsigned Q45 = pk2(C[12], C[13]);  // (24,25)/(28,29)
        unsigned Q67 = pk2(C[14], C[15]);  // (26,27)/(30,31)
        unsigned XP01 = (unsigned)__shfl_xor((int)P01, 32, 64);
        unsigned XP23 = (unsigned)__shfl_xor((int)P23, 32, 64);
        unsigned XP45 = (unsigned)__shfl_xor((int)P45, 32, 64);
        unsigned XP67 = (unsigned)__shfl_xor((int)P67, 32, 64);
        unsigned XQ01 = (unsigned)__shfl_xor((int)Q01, 32, 64);
        unsigned XQ23 = (unsigned)__shfl_xor((int)Q23, 32, 64);
        unsigned XQ45 = (unsigned)__shfl_xor((int)Q45, 32, 64);
        unsigned XQ67 = (unsigned)__shfl_xor((int)Q67, 32, 64);
        B0.u[0] = hi ? XP45 : P01;   // k=h*8+{0,1}
        B0.u[1] = hi ? XP67 : P23;   // k=h*8+{2,3}
        B0.u[2] = hi ? P45  : XP01;  // k=h*8+{4,5}
        B0.u[3] = hi ? P67  : XP23;  // k=h*8+{6,7}
        B1.u[0] = hi ? XQ45 : Q01;   // k=16+h*8+{0,1}
        B1.u[1] = hi ? XQ67 : Q23;
        B1.u[2] = hi ? Q45  : XQ01;
        B1.u[3] = hi ? Q67  : XQ23;
    }

    // store final C as bf16
    #pragma unroll
    for (int s = 0; s < 16; ++s)
        outM[s * 64 + lane] = (unsigned short)(pk2(C[s], 0.0f) & 0xFFFFu);
    if (lane == 0) wsK[item * NCHUNK + chunk] = creg;
}

// ---------------- Phase 2: combine + scores ----------------
__global__ __launch_bounds__(64)
void crf_phase2(const float* __restrict__ feats,
                const int*   __restrict__ labels,
                const int*   __restrict__ lengths,
                const float* __restrict__ trans,
                const unsigned short* __restrict__ wsM,
                const int*            __restrict__ wsK,
                float* __restrict__ out)
{
    __shared__ float s_p[32];
    const int j   = threadIdx.x;
    const int j32 = j & 31;
    const int b   = blockIdx.x;

    const float* fb = feats  + (size_t)b * NS * NTAG;
    const int*   lb = labels + (size_t)b * NS;
    const int    len = lengths[b];

    float p = fexp2((fb[j32] + trans[(TSTART << 5) + j32]) * LOG2E);
    int cacc = 0;

    // row m=j32 lives at slot s, half hh: m = (s&3)+8*(s>>2)+4*hh
    const int s  = (j32 & 3) | (((j32 >> 3) & 3) << 2);
    const int hh = (j32 >> 2) & 1;
    const unsigned short* Mb = wsM + ((size_t)(b * NCHUNK) << 10);

    uint4 cur[4];
    {
        const uint4* rp = (const uint4*)(Mb + s * 64 + hh * 32);
        cur[0] = rp[0]; cur[1] = rp[1]; cur[2] = rp[2]; cur[3] = rp[3];
    }

    for (int c = 0; c < NCHUNK; ++c) {
        uint4 nxt[4];
        if (c + 1 < NCHUNK) {
            const uint4* rp = (const uint4*)(Mb + ((size_t)(c + 1) << 10) + s * 64 + hh * 32);
            nxt[0] = rp[0]; nxt[1] = rp[1]; nxt[2] = rp[2]; nxt[3] = rp[3];
        }
        cacc += wsK[b * NCHUNK + c];

        __syncthreads();
        s_p[j32] = p;
        __syncthreads();

        const unsigned short* rw = (const unsigned short*)cur;
        float q = 0.0f;
        #pragma unroll
        for (int n = 0; n < 32; ++n) {
            float Mv = __uint_as_float(((unsigned)rw[n]) << 16);
            q = fmaf(Mv, s_p[n], q);
        }

        int bits = __builtin_amdgcn_readfirstlane(__float_as_int(q));
        int e_ = min(max((bits >> 23) & 0xFF, 1), 254);
        cacc += e_ - 127;
        p = q * __uint_as_float((unsigned)(254 - e_) << 23);   // q * 2^-k

        cur[0] = nxt[0]; cur[1] = nxt[1]; cur[2] = nxt[2]; cur[3] = nxt[3];
    }

    // forward score (p duplicated mod 32 across halves)
    float ssum = p;
    #pragma unroll
    for (int mm = 1; mm <= 16; mm <<= 1)
        ssum += __shfl_xor(ssum, mm, 64);
    float fwd = (float)cacc * LN2 + logf(ssum);

    // gold score: parallel gather (R4 tail)
    float gold = 0.0f;
    #pragma unroll
    for (int k = 0; k < 8; ++k) {
        int tt = (k << 6) + j;
        if (tt < len) {
            int lab_t = lb[tt];
            gold += fb[(size_t)tt * NTAG + lab_t];
            if (tt > 0)
                gold += trans[(lb[tt - 1] << 5) + lab_t];
            else
                gold += trans[(TSTART << 5) + lab_t];
            if (tt == len - 1)
                gold += trans[(lab_t << 5) + TSTOP];
        }
    }
    #pragma unroll
    for (int mm = 1; mm <= 32; mm <<= 1)
        gold += __shfl_xor(gold, mm, 64);

    if (j == 0)
        atomicAdd(out, (fwd - gold) * (1.0f / 1024.0f));
}

extern "C" void kernel_launch(void* const* d_in, const int* in_sizes, int n_in,
                              void* d_out, int out_size, void* d_ws, size_t ws_size,
                              hipStream_t stream) {
    const float* feats   = (const float*)d_in[0];
    const int*   labels  = (const int*)d_in[1];
    const int*   lengths = (const int*)d_in[2];
    const float* trans   = (const float*)d_in[3];
    float*       out     = (float*)d_out;

    unsigned short* wsM = (unsigned short*)d_ws;                 // 16 MiB
    int*            wsK = (int*)((char*)d_ws + (size_t)NB * NCHUNK * 1024 * 2);

    hipMemsetAsync(out, 0, sizeof(float) * (size_t)out_size, stream);
    crf_phase1<<<dim3(NB * NCHUNK / 4), dim3(256), 0, stream>>>(feats, lengths, trans, wsM, wsK);
    crf_phase2<<<dim3(NB), dim3(64), 0, stream>>>(feats, labels, lengths, trans, wsM, wsK, out);
}

// Round 7
// 193.985 us; speedup vs baseline: 1.0940x; 1.0940x over previous
//
#include <hip/hip_runtime.h>
#include <hip/hip_bf16.h>
#include <math.h>

// BERT-CRF forward NLL on MI355X — chunked associative-scan formulation.
// p_t = D_t E^T p_{t-1}  (D_t = diag(exp(feat_t)), E = exp(trans)).
// Phase 1: per (item, 64-step chunk): M_c = prod_t (D_t E^T) via
//   2x mfma_f32_32x32x16_bf16 per step; per-step 2^-k renorm folded into A.
//   C->B relayout via v_permlane32_swap_b32 (4 VALU ops, no DS on the chain).
//   Step loop statically unrolled by 4 with named prefetch registers.
// Phase 2: per item, p = M_7 ... M_0 p_0, forward score, gold gather tail.

constexpr int NTAG = 32;
constexpr int TSTART = 30;
constexpr int TSTOP = 31;
constexpr int NB = 1024;
constexpr int NS = 512;
constexpr int CHUNK = 64;
constexpr int NCHUNK = 8;

constexpr float LOG2E = 1.44269504088896340736f;
constexpr float LN2   = 0.69314718055994530942f;

typedef short    bf16x8 __attribute__((ext_vector_type(8)));
typedef float    f32x16 __attribute__((ext_vector_type(16)));
typedef unsigned u32x2  __attribute__((ext_vector_type(2)));

union PKU { bf16x8 v; unsigned u[4]; };

__device__ __forceinline__ float fexp2(float x) {
#if __has_builtin(__builtin_amdgcn_exp2f)
    return __builtin_amdgcn_exp2f(x);
#else
    return exp2f(x);
#endif
}
__device__ __forceinline__ unsigned pk2(float a, float b) {
    union { __hip_bfloat162 h; unsigned u; } cv;
    cv.h = __float22bfloat162_rn(make_float2(a, b));
    return cv.u;
}

// ---------------- Phase 1: per-(item,chunk) matrix products ----------------
__global__ __launch_bounds__(256, 4)
void crf_phase1(const float* __restrict__ feats,
                const int*   __restrict__ lengths,
                const float* __restrict__ trans,
                unsigned short* __restrict__ wsM,   // [item][chunk][s:16][lane:64]
                int*            __restrict__ wsK)   // [item][chunk]
{
    const int lane  = threadIdx.x & 63;
    const int wid   = threadIdx.x >> 6;
    const int gid   = blockIdx.x * 4 + wid;
    const int item  = gid >> 3;
    const int chunk = gid & 7;
    const int m     = lane & 31;   // A row / C col index
    const int h     = lane >> 5;

    const int len  = lengths[item];
    const int base = chunk * CHUNK;               // steps t = base+1 .. base+cnt
    int cnt = len - 1 - base;
    int cmax = min(CHUNK, NS - 1 - base);
    cnt = max(0, min(cnt, cmax));

    unsigned short* outM = wsM + ((size_t)(item * NCHUNK + chunk) << 10);

    if (cnt == 0) {
        // M = identity, creg = 0
        #pragma unroll
        for (int s = 0; s < 16; ++s) {
            int mm = (s & 3) + 8 * (s >> 2) + 4 * h;
            outM[s * 64 + lane] = (mm == m) ? (unsigned short)0x3F80 : (unsigned short)0;
        }
        if (lane == 0) wsK[item * NCHUNK + chunk] = 0;
        return;
    }

    // Static A fragments: E^T[m][k] = exp(trans[k][m]), k = g*16 + h*8 + e
    float Efrag[2][8];
    #pragma unroll
    for (int g = 0; g < 2; ++g)
        #pragma unroll
        for (int e = 0; e < 8; ++e) {
            int k = g * 16 + h * 8 + e;
            Efrag[g][e] = fexp2(trans[k * 32 + m] * LOG2E);
        }

    // Seed B = I (B_g element e: k = g*16 + h*8 + e, col n = m)
    PKU B0, B1;
    #pragma unroll
    for (int r = 0; r < 4; ++r) {
        int k0 = h * 8 + 2 * r;
        B0.u[r] = ((k0 == m) ? 0x3F80u : 0u) | (((k0 + 1 == m) ? 0x3F80u : 0u) << 16);
        int k2 = 16 + h * 8 + 2 * r;
        B1.u[r] = ((k2 == m) ? 0x3F80u : 0u) | (((k2 + 1 == m) ? 0x3F80u : 0u) << 16);
    }

    const float* fb = feats + (size_t)item * NS * NTAG;

    f32x16 zc;
    #pragma unroll
    for (int e = 0; e < 16; ++e) zc[e] = 0.0f;

    int creg = 0, knext = 0;
    f32x16 C;

    #define P1_STEP(FV)                                                          \
    {                                                                            \
        creg += knext;                                                           \
        float ex = fexp2(fmaf((FV), LOG2E, -(float)knext));                      \
        PKU A0, A1;                                                              \
        _Pragma("unroll")                                                        \
        for (int r = 0; r < 4; ++r) {                                            \
            A0.u[r] = pk2(ex * Efrag[0][2 * r], ex * Efrag[0][2 * r + 1]);       \
            A1.u[r] = pk2(ex * Efrag[1][2 * r], ex * Efrag[1][2 * r + 1]);       \
        }                                                                        \
        C = __builtin_amdgcn_mfma_f32_32x32x16_bf16(A0.v, B0.v, zc, 0, 0, 0);    \
        C = __builtin_amdgcn_mfma_f32_32x32x16_bf16(A1.v, B1.v, C,  0, 0, 0);    \
        int bits = __builtin_amdgcn_readfirstlane(__float_as_int(C[0]));         \
        int e_ = min(max((bits >> 23) & 0xFF, 1), 254);                          \
        knext = e_ - 127;                                                        \
        unsigned P01 = pk2(C[0],  C[1]);                                         \
        unsigned P23 = pk2(C[2],  C[3]);                                         \
        unsigned P45 = pk2(C[4],  C[5]);                                         \
        unsigned P67 = pk2(C[6],  C[7]);                                         \
        unsigned Q01 = pk2(C[8],  C[9]);                                         \
        unsigned Q23 = pk2(C[10], C[11]);                                        \
        unsigned Q45 = pk2(C[12], C[13]);                                        \
        unsigned Q67 = pk2(C[14], C[15]);                                        \
        u32x2 r0 = __builtin_amdgcn_permlane32_swap(P01, P45, false, false);     \
        u32x2 r1 = __builtin_amdgcn_permlane32_swap(P23, P67, false, false);     \
        u32x2 r2 = __builtin_amdgcn_permlane32_swap(Q01, Q45, false, false);     \
        u32x2 r3 = __builtin_amdgcn_permlane32_swap(Q23, Q67, false, false);     \
        B0.u[0] = r0.x; B0.u[2] = r0.y;                                          \
        B0.u[1] = r1.x; B0.u[3] = r1.y;                                          \
        B1.u[0] = r2.x; B1.u[2] = r2.y;                                          \
        B1.u[1] = r3.x; B1.u[3] = r3.y;                                          \
    }

    // statically-unrolled 4-step pipeline with named prefetch registers
    const int tb = base + 1;
    #define P1_CIDX(X) ((size_t)min(tb + (X), NS - 1) * NTAG + m)
    float f0 = fb[P1_CIDX(0)];
    float f1 = fb[P1_CIDX(1)];
    float f2 = fb[P1_CIDX(2)];
    float f3 = fb[P1_CIDX(3)];

    int i = 0;
    for (; i + 4 <= cnt; i += 4) {
        float n0 = fb[P1_CIDX(i + 4)];
        float n1 = fb[P1_CIDX(i + 5)];
        float n2 = fb[P1_CIDX(i + 6)];
        float n3 = fb[P1_CIDX(i + 7)];
        P1_STEP(f0)
        P1_STEP(f1)
        P1_STEP(f2)
        P1_STEP(f3)
        f0 = n0; f1 = n1; f2 = n2; f3 = n3;
    }
    // remainder (<=3): f0..f2 hold feats for steps i..i+2
    if (i < cnt)     P1_STEP(f0)
    if (i + 1 < cnt) P1_STEP(f1)
    if (i + 2 < cnt) P1_STEP(f2)
    #undef P1_STEP
    #undef P1_CIDX

    // store final C as bf16
    #pragma unroll
    for (int s = 0; s < 16; ++s)
        outM[s * 64 + lane] = (unsigned short)(pk2(C[s], 0.0f) & 0xFFFFu);
    if (lane == 0) wsK[item * NCHUNK + chunk] = creg;
}

// ---------------- Phase 2: combine + scores ----------------
__global__ __launch_bounds__(64)
void crf_phase2(const float* __restrict__ feats,
                const int*   __restrict__ labels,
                const int*   __restrict__ lengths,
                const float* __restrict__ trans,
                const unsigned short* __restrict__ wsM,
                const int*            __restrict__ wsK,
                float* __restrict__ out)
{
    __shared__ float s_p[32];
    const int j   = threadIdx.x;
    const int j32 = j & 31;
    const int b   = blockIdx.x;

    const float* fb = feats  + (size_t)b * NS * NTAG;
    const int*   lb = labels + (size_t)b * NS;
    const int    len = lengths[b];

    float p = fexp2((fb[j32] + trans[(TSTART << 5) + j32]) * LOG2E);
    int cacc = 0;

    // row m=j32 lives at slot s, half hh: m = (s&3)+8*(s>>2)+4*hh
    const int s  = (j32 & 3) | (((j32 >> 3) & 3) << 2);
    const int hh = (j32 >> 2) & 1;
    const unsigned short* Mb = wsM + ((size_t)(b * NCHUNK) << 10);

    uint4 cur[4];
    {
        const uint4* rp = (const uint4*)(Mb + s * 64 + hh * 32);
        cur[0] = rp[0]; cur[1] = rp[1]; cur[2] = rp[2]; cur[3] = rp[3];
    }

    for (int c = 0; c < NCHUNK; ++c) {
        uint4 nxt[4];
        if (c + 1 < NCHUNK) {
            const uint4* rp = (const uint4*)(Mb + ((size_t)(c + 1) << 10) + s * 64 + hh * 32);
            nxt[0] = rp[0]; nxt[1] = rp[1]; nxt[2] = rp[2]; nxt[3] = rp[3];
        }
        cacc += wsK[b * NCHUNK + c];

        __syncthreads();
        s_p[j32] = p;
        __syncthreads();

        const unsigned short* rw = (const unsigned short*)cur;
        float q = 0.0f;
        #pragma unroll
        for (int n = 0; n < 32; ++n) {
            float Mv = __uint_as_float(((unsigned)rw[n]) << 16);
            q = fmaf(Mv, s_p[n], q);
        }

        int bits = __builtin_amdgcn_readfirstlane(__float_as_int(q));
        int e_ = min(max((bits >> 23) & 0xFF, 1), 254);
        cacc += e_ - 127;
        p = q * __uint_as_float((unsigned)(254 - e_) << 23);   // q * 2^-k

        cur[0] = nxt[0]; cur[1] = nxt[1]; cur[2] = nxt[2]; cur[3] = nxt[3];
    }

    // forward score (p duplicated mod 32 across halves)
    float ssum = p;
    #pragma unroll
    for (int mm = 1; mm <= 16; mm <<= 1)
        ssum += __shfl_xor(ssum, mm, 64);
    float fwd = (float)cacc * LN2 + logf(ssum);

    // gold score: parallel gather
    float gold = 0.0f;
    #pragma unroll
    for (int k = 0; k < 8; ++k) {
        int tt = (k << 6) + j;
        if (tt < len) {
            int lab_t = lb[tt];
            gold += fb[(size_t)tt * NTAG + lab_t];
            if (tt > 0)
                gold += trans[(lb[tt - 1] << 5) + lab_t];
            else
                gold += trans[(TSTART << 5) + lab_t];
            if (tt == len - 1)
                gold += trans[(lab_t << 5) + TSTOP];
        }
    }
    #pragma unroll
    for (int mm = 1; mm <= 32; mm <<= 1)
        gold += __shfl_xor(gold, mm, 64);

    if (j == 0)
        atomicAdd(out, (fwd - gold) * (1.0f / 1024.0f));
}

extern "C" void kernel_launch(void* const* d_in, const int* in_sizes, int n_in,
                              void* d_out, int out_size, void* d_ws, size_t ws_size,
                              hipStream_t stream) {
    const float* feats   = (const float*)d_in[0];
    const int*   labels  = (const int*)d_in[1];
    const int*   lengths = (const int*)d_in[2];
    const float* trans   = (const float*)d_in[3];
    float*       out     = (float*)d_out;

    unsigned short* wsM = (unsigned short*)d_ws;                 // 16 MiB
    int*            wsK = (int*)((char*)d_ws + (size_t)NB * NCHUNK * 1024 * 2);

    hipMemsetAsync(out, 0, sizeof(float) * (size_t)out_size, stream);
    crf_phase1<<<dim3(NB * NCHUNK / 4), dim3(256), 0, stream>>>(feats, lengths, trans, wsM, wsK);
    crf_phase2<<<dim3(NB), dim3(64), 0, stream>>>(feats, labels, lengths, trans, wsM, wsK, out);
}

// Round 8
// 189.802 us; speedup vs baseline: 1.1181x; 1.0220x over previous
//
#include <hip/hip_runtime.h>
#include <hip/hip_bf16.h>
#include <math.h>

// BERT-CRF forward NLL on MI355X — chunked associative-scan formulation.
// p_t = D_t E^T p_{t-1}  (D_t = diag(exp(feat_t)), E = exp(trans)).
// Phase 1: per (item, chunk): M_c = prod_t (D_t E^T) via 2x
//   mfma_f32_32x32x16_bf16 per step; per-step 2^-k renorm folded into A.
//   C->B relayout via v_permlane32_swap_b32 (verified exact in R6/R7).
//   NEW (R8): balanced chunk partition (8 equal chunks per item) and 2-way
//   ILP — each wave runs TWO chunks of its item with steps interleaved, so
//   the second chain fills the first chain's MFMA->cvt->permlane stalls.
// Phase 2: per item, p = M_7 ... M_0 p_0, forward score, gold gather tail.

constexpr int NTAG = 32;
constexpr int TSTART = 30;
constexpr int TSTOP = 31;
constexpr int NB = 1024;
constexpr int NS = 512;
constexpr int NCHUNK = 8;

constexpr float LOG2E = 1.44269504088896340736f;
constexpr float LN2   = 0.69314718055994530942f;

typedef short    bf16x8 __attribute__((ext_vector_type(8)));
typedef float    f32x16 __attribute__((ext_vector_type(16)));
typedef float    f32x2  __attribute__((ext_vector_type(2)));
typedef unsigned u32x2  __attribute__((ext_vector_type(2)));

union PKU { bf16x8 v; unsigned u[4]; };

__device__ __forceinline__ float fexp2(float x) {
#if __has_builtin(__builtin_amdgcn_exp2f)
    return __builtin_amdgcn_exp2f(x);
#else
    return exp2f(x);
#endif
}
__device__ __forceinline__ unsigned pk2(float a, float b) {
    union { __hip_bfloat162 h; unsigned u; } cv;
    cv.h = __float22bfloat162_rn(make_float2(a, b));
    return cv.u;
}

// ---------------- Phase 1: per-(item,chunk) matrix products ----------------
__global__ __launch_bounds__(256, 4)
void crf_phase1(const float* __restrict__ feats,
                const int*   __restrict__ lengths,
                const float* __restrict__ trans,
                unsigned short* __restrict__ wsM,   // [item][chunk][s:16][lane:64]
                int*            __restrict__ wsK)   // [item][chunk]
{
    const int lane = threadIdx.x & 63;
    const int wid  = threadIdx.x >> 6;
    const int item = blockIdx.x;
    const int m    = lane & 31;   // A row / C col index
    const int h    = lane >> 5;
    const int cA   = wid * 2;
    const int cB   = cA + 1;

    const int len    = lengths[item];
    const int nsteps = max(len - 1, 0);            // 0..511
    const int bsz    = nsteps >> 3;
    const int extra  = nsteps & 7;
    const int startA = cA * bsz + min(cA, extra);
    const int cntA   = bsz + (cA < extra ? 1 : 0); // <= 64
    const int startB = cB * bsz + min(cB, extra);
    const int cntB   = bsz + (cB < extra ? 1 : 0); // cntA-1 <= cntB <= cntA

    // Static A fragments as float2: E^T[m][k] = exp(trans[k][m])
    f32x2 Efrag2[8];
    #pragma unroll
    for (int g = 0; g < 2; ++g)
        #pragma unroll
        for (int r = 0; r < 4; ++r) {
            int k0 = g * 16 + h * 8 + 2 * r;
            f32x2 e;
            e.x = fexp2(trans[k0 * 32 + m] * LOG2E);
            e.y = fexp2(trans[(k0 + 1) * 32 + m] * LOG2E);
            Efrag2[g * 4 + r] = e;
        }

    // Seed B = I for both chains (B_g element e: k = g*16 + h*8 + e, col = m)
    PKU B0A, B1A, B0B, B1B;
    #pragma unroll
    for (int r = 0; r < 4; ++r) {
        int k0 = h * 8 + 2 * r;
        unsigned lo = ((k0 == m) ? 0x3F80u : 0u) | (((k0 + 1 == m) ? 0x3F80u : 0u) << 16);
        int k2 = 16 + h * 8 + 2 * r;
        unsigned hi2 = ((k2 == m) ? 0x3F80u : 0u) | (((k2 + 1 == m) ? 0x3F80u : 0u) << 16);
        B0A.u[r] = lo;  B1A.u[r] = hi2;
        B0B.u[r] = lo;  B1B.u[r] = hi2;
    }

    const float* fb = feats + (size_t)item * NS * NTAG;

    f32x16 zc;
    #pragma unroll
    for (int e = 0; e < 16; ++e) zc[e] = 0.0f;

    f32x16 CA, CB;
    int cregA = 0, knA = 0, cregB = 0, knB = 0;

    #define P1_STEP(C_, B0_, B1_, KN_, CR_, FV)                                  \
    {                                                                            \
        CR_ += KN_;                                                              \
        float ex = fexp2(fmaf((FV), LOG2E, -(float)KN_));                        \
        f32x2 ex2; ex2.x = ex; ex2.y = ex;                                       \
        PKU A0, A1;                                                              \
        _Pragma("unroll")                                                        \
        for (int r = 0; r < 4; ++r) {                                            \
            f32x2 p0 = ex2 * Efrag2[r];                                          \
            f32x2 p1 = ex2 * Efrag2[4 + r];                                      \
            A0.u[r] = pk2(p0.x, p0.y);                                           \
            A1.u[r] = pk2(p1.x, p1.y);                                           \
        }                                                                        \
        C_ = __builtin_amdgcn_mfma_f32_32x32x16_bf16(A0.v, B0_.v, zc, 0, 0, 0);  \
        C_ = __builtin_amdgcn_mfma_f32_32x32x16_bf16(A1.v, B1_.v, C_, 0, 0, 0);  \
        int bits = __builtin_amdgcn_readfirstlane(__float_as_int(C_[0]));        \
        int e_ = min(max((bits >> 23) & 0xFF, 1), 254);                          \
        KN_ = e_ - 127;                                                          \
        unsigned P01 = pk2(C_[0],  C_[1]);                                       \
        unsigned P23 = pk2(C_[2],  C_[3]);                                       \
        unsigned P45 = pk2(C_[4],  C_[5]);                                       \
        unsigned P67 = pk2(C_[6],  C_[7]);                                       \
        unsigned Q01 = pk2(C_[8],  C_[9]);                                       \
        unsigned Q23 = pk2(C_[10], C_[11]);                                      \
        unsigned Q45 = pk2(C_[12], C_[13]);                                      \
        unsigned Q67 = pk2(C_[14], C_[15]);                                      \
        u32x2 r0 = __builtin_amdgcn_permlane32_swap(P01, P45, false, false);     \
        u32x2 r1 = __builtin_amdgcn_permlane32_swap(P23, P67, false, false);     \
        u32x2 r2 = __builtin_amdgcn_permlane32_swap(Q01, Q45, false, false);     \
        u32x2 r3 = __builtin_amdgcn_permlane32_swap(Q23, Q67, false, false);     \
        B0_.u[0] = r0.x; B0_.u[2] = r0.y;                                        \
        B0_.u[1] = r1.x; B0_.u[3] = r1.y;                                        \
        B1_.u[0] = r2.x; B1_.u[2] = r2.y;                                        \
        B1_.u[1] = r3.x; B1_.u[3] = r3.y;                                        \
    }

    const int tbA = 1 + startA, tbB = 1 + startB;
    #define IDXA(X) ((size_t)min(tbA + (X), NS - 1) * NTAG + m)
    #define IDXB(X) ((size_t)min(tbB + (X), NS - 1) * NTAG + m)
    float fA0 = fb[IDXA(0)], fA1 = fb[IDXA(1)], fA2 = fb[IDXA(2)], fA3 = fb[IDXA(3)];
    float fB0 = fb[IDXB(0)], fB1 = fb[IDXB(1)], fB2 = fb[IDXB(2)], fB3 = fb[IDXB(3)];

    int i = 0;
    for (; i + 4 <= cntB; i += 4) {
        float nA0 = fb[IDXA(i + 4)], nA1 = fb[IDXA(i + 5)];
        float nA2 = fb[IDXA(i + 6)], nA3 = fb[IDXA(i + 7)];
        float nB0 = fb[IDXB(i + 4)], nB1 = fb[IDXB(i + 5)];
        float nB2 = fb[IDXB(i + 6)], nB3 = fb[IDXB(i + 7)];
        P1_STEP(CA, B0A, B1A, knA, cregA, fA0)
        P1_STEP(CB, B0B, B1B, knB, cregB, fB0)
        P1_STEP(CA, B0A, B1A, knA, cregA, fA1)
        P1_STEP(CB, B0B, B1B, knB, cregB, fB1)
        P1_STEP(CA, B0A, B1A, knA, cregA, fA2)
        P1_STEP(CB, B0B, B1B, knB, cregB, fB2)
        P1_STEP(CA, B0A, B1A, knA, cregA, fA3)
        P1_STEP(CB, B0B, B1B, knB, cregB, fB3)
        fA0 = nA0; fA1 = nA1; fA2 = nA2; fA3 = nA3;
        fB0 = nB0; fB1 = nB1; fB2 = nB2; fB3 = nB3;
    }
    const int r = cntB - i;   // 0..3, wave-uniform
    if (r >= 1) { P1_STEP(CA, B0A, B1A, knA, cregA, fA0)
                  P1_STEP(CB, B0B, B1B, knB, cregB, fB0) }
    if (r >= 2) { P1_STEP(CA, B0A, B1A, knA, cregA, fA1)
                  P1_STEP(CB, B0B, B1B, knB, cregB, fB1) }
    if (r >= 3) { P1_STEP(CA, B0A, B1A, knA, cregA, fA2)
                  P1_STEP(CB, B0B, B1B, knB, cregB, fB2) }
    if (cntA > cntB) {
        float fx = (r == 0) ? fA0 : (r == 1) ? fA1 : (r == 2) ? fA2 : fA3;
        P1_STEP(CA, B0A, B1A, knA, cregA, fx)
    }
    #undef P1_STEP
    #undef IDXA
    #undef IDXB

    // store both chunk matrices (identity if the chunk was empty)
    unsigned short* outA = wsM + ((size_t)(item * NCHUNK + cA) << 10);
    unsigned short* outB = wsM + ((size_t)(item * NCHUNK + cB) << 10);
    #pragma unroll
    for (int s = 0; s < 16; ++s) {
        int rowm = (s & 3) + 8 * (s >> 2) + 4 * h;
        unsigned short idv = (rowm == m) ? (unsigned short)0x3F80 : (unsigned short)0;
        unsigned short va = (cntA > 0) ? (unsigned short)(pk2(CA[s], 0.0f) & 0xFFFFu) : idv;
        unsigned short vb = (cntB > 0) ? (unsigned short)(pk2(CB[s], 0.0f) & 0xFFFFu) : idv;
        outA[s * 64 + lane] = va;
        outB[s * 64 + lane] = vb;
    }
    if (lane == 0) {
        wsK[item * NCHUNK + cA] = cregA;
        wsK[item * NCHUNK + cB] = cregB;
    }
}

// ---------------- Phase 2: combine + scores ----------------
__global__ __launch_bounds__(64)
void crf_phase2(const float* __restrict__ feats,
                const int*   __restrict__ labels,
                const int*   __restrict__ lengths,
                const float* __restrict__ trans,
                const unsigned short* __restrict__ wsM,
                const int*            __restrict__ wsK,
                float* __restrict__ out)
{
    __shared__ float s_p[32];
    const int j   = threadIdx.x;
    const int j32 = j & 31;
    const int b   = blockIdx.x;

    const float* fb = feats  + (size_t)b * NS * NTAG;
    const int*   lb = labels + (size_t)b * NS;
    const int    len = lengths[b];

    float p = fexp2((fb[j32] + trans[(TSTART << 5) + j32]) * LOG2E);
    int cacc = 0;

    // row m=j32 lives at slot s, half hh: m = (s&3)+8*(s>>2)+4*hh
    const int s  = (j32 & 3) | (((j32 >> 3) & 3) << 2);
    const int hh = (j32 >> 2) & 1;
    const unsigned short* Mb = wsM + ((size_t)(b * NCHUNK) << 10);

    uint4 cur[4];
    {
        const uint4* rp = (const uint4*)(Mb + s * 64 + hh * 32);
        cur[0] = rp[0]; cur[1] = rp[1]; cur[2] = rp[2]; cur[3] = rp[3];
    }

    for (int c = 0; c < NCHUNK; ++c) {
        uint4 nxt[4];
        if (c + 1 < NCHUNK) {
            const uint4* rp = (const uint4*)(Mb + ((size_t)(c + 1) << 10) + s * 64 + hh * 32);
            nxt[0] = rp[0]; nxt[1] = rp[1]; nxt[2] = rp[2]; nxt[3] = rp[3];
        }
        cacc += wsK[b * NCHUNK + c];

        __syncthreads();
        s_p[j32] = p;
        __syncthreads();

        const unsigned short* rw = (const unsigned short*)cur;
        float q0 = 0.f, q1 = 0.f, q2 = 0.f, q3 = 0.f;
        #pragma unroll
        for (int n = 0; n < 32; n += 4) {
            q0 = fmaf(__uint_as_float(((unsigned)rw[n + 0]) << 16), s_p[n + 0], q0);
            q1 = fmaf(__uint_as_float(((unsigned)rw[n + 1]) << 16), s_p[n + 1], q1);
            q2 = fmaf(__uint_as_float(((unsigned)rw[n + 2]) << 16), s_p[n + 2], q2);
            q3 = fmaf(__uint_as_float(((unsigned)rw[n + 3]) << 16), s_p[n + 3], q3);
        }
        float q = (q0 + q1) + (q2 + q3);

        int bits = __builtin_amdgcn_readfirstlane(__float_as_int(q));
        int e_ = min(max((bits >> 23) & 0xFF, 1), 254);
        cacc += e_ - 127;
        p = q * __uint_as_float((unsigned)(254 - e_) << 23);   // q * 2^-k

        cur[0] = nxt[0]; cur[1] = nxt[1]; cur[2] = nxt[2]; cur[3] = nxt[3];
    }

    // forward score (p duplicated mod 32 across halves)
    float ssum = p;
    #pragma unroll
    for (int mm = 1; mm <= 16; mm <<= 1)
        ssum += __shfl_xor(ssum, mm, 64);
    float fwd = (float)cacc * LN2 + logf(ssum);

    // gold score: parallel gather
    float gold = 0.0f;
    #pragma unroll
    for (int k = 0; k < 8; ++k) {
        int tt = (k << 6) + j;
        if (tt < len) {
            int lab_t = lb[tt];
            gold += fb[(size_t)tt * NTAG + lab_t];
            if (tt > 0)
                gold += trans[(lb[tt - 1] << 5) + lab_t];
            else
                gold += trans[(TSTART << 5) + lab_t];
            if (tt == len - 1)
                gold += trans[(lab_t << 5) + TSTOP];
        }
    }
    #pragma unroll
    for (int mm = 1; mm <= 32; mm <<= 1)
        gold += __shfl_xor(gold, mm, 64);

    if (j == 0)
        atomicAdd(out, (fwd - gold) * (1.0f / 1024.0f));
}

extern "C" void kernel_launch(void* const* d_in, const int* in_sizes, int n_in,
                              void* d_out, int out_size, void* d_ws, size_t ws_size,
                              hipStream_t stream) {
    const float* feats   = (const float*)d_in[0];
    const int*   labels  = (const int*)d_in[1];
    const int*   lengths = (const int*)d_in[2];
    const float* trans   = (const float*)d_in[3];
    float*       out     = (float*)d_out;

    unsigned short* wsM = (unsigned short*)d_ws;                 // 16 MiB
    int*            wsK = (int*)((char*)d_ws + (size_t)NB * NCHUNK * 1024 * 2);

    hipMemsetAsync(out, 0, sizeof(float) * (size_t)out_size, stream);
    crf_phase1<<<dim3(NB), dim3(256), 0, stream>>>(feats, lengths, trans, wsM, wsK);
    crf_phase2<<<dim3(NB), dim3(64), 0, stream>>>(feats, labels, lengths, trans, wsM, wsK, out);
}

// Round 9
// 180.817 us; speedup vs baseline: 1.1737x; 1.0497x over previous
//
#include <hip/hip_runtime.h>
#include <hip/hip_bf16.h>
#include <math.h>

// BERT-CRF forward NLL on MI355X — chunked associative-scan formulation.
// p_t = D_t E^T p_{t-1}  (D_t = diag(exp(feat_t)), E = exp(trans)).
// Phase 1 (per item block, 4 waves, 2 chunk-chains per wave):
//   M_c = prod_t (D_t E^T) via 2x mfma_f32_32x32x16_bf16 per step.
//   R9: renorm every 4 steps with a 3-step-stale exponent (breaks the
//   MFMA->readfirstlane->exp2 serial chain); feat prefetch 2 iterations deep;
//   gold score fused into phase1 (parallel gather over 256 threads).
// Phase 2: per item, p = M_7 ... M_0 p_0 (8 matvecs), forward score only.

constexpr int NTAG = 32;
constexpr int TSTART = 30;
constexpr int TSTOP = 31;
constexpr int NB = 1024;
constexpr int NS = 512;
constexpr int NCHUNK = 8;

constexpr float LOG2E = 1.44269504088896340736f;
constexpr float LN2   = 0.69314718055994530942f;

typedef short    bf16x8 __attribute__((ext_vector_type(8)));
typedef float    f32x16 __attribute__((ext_vector_type(16)));
typedef float    f32x2  __attribute__((ext_vector_type(2)));
typedef unsigned u32x2  __attribute__((ext_vector_type(2)));

union PKU { bf16x8 v; unsigned u[4]; };

__device__ __forceinline__ float fexp2(float x) {
#if __has_builtin(__builtin_amdgcn_exp2f)
    return __builtin_amdgcn_exp2f(x);
#else
    return exp2f(x);
#endif
}
__device__ __forceinline__ unsigned pk2(float a, float b) {
    union { __hip_bfloat162 h; unsigned u; } cv;
    cv.h = __float22bfloat162_rn(make_float2(a, b));
    return cv.u;
}

// ---------------- Phase 1 ----------------
__global__ __launch_bounds__(256, 4)
void crf_phase1(const float* __restrict__ feats,
                const int*   __restrict__ labels,
                const int*   __restrict__ lengths,
                const float* __restrict__ trans,
                unsigned short* __restrict__ wsM,   // [item][chunk][s:16][lane:64]
                int*            __restrict__ wsK,   // [item][chunk]
                float*          __restrict__ out)
{
    __shared__ float s_g[4];
    const int tid  = threadIdx.x;
    const int lane = tid & 63;
    const int wid  = tid >> 6;
    const int item = blockIdx.x;
    const int m    = lane & 31;
    const int h    = lane >> 5;
    const int cX   = wid * 2;
    const int cY   = cX + 1;

    const int len    = lengths[item];
    const int nsteps = max(len - 1, 0);
    const int bsz    = nsteps >> 3;
    const int extra  = nsteps & 7;
    const int startX = cX * bsz + min(cX, extra);
    const int cntX   = bsz + (cX < extra ? 1 : 0);
    const int startY = cY * bsz + min(cY, extra);
    const int cntY   = bsz + (cY < extra ? 1 : 0);   // cntX >= cntY >= cntX-1

    // Static A fragments: E^T[m][k] = exp(trans[k][m]), k = g*16 + h*8 + e
    f32x2 Efrag2[8];
    #pragma unroll
    for (int g = 0; g < 2; ++g)
        #pragma unroll
        for (int r = 0; r < 4; ++r) {
            int k0 = g * 16 + h * 8 + 2 * r;
            f32x2 e;
            e.x = fexp2(trans[k0 * 32 + m] * LOG2E);
            e.y = fexp2(trans[(k0 + 1) * 32 + m] * LOG2E);
            Efrag2[g * 4 + r] = e;
        }

    // Seed B = I for both chains
    PKU B0X, B1X, B0Y, B1Y;
    #pragma unroll
    for (int r = 0; r < 4; ++r) {
        int k0 = h * 8 + 2 * r;
        unsigned lo = ((k0 == m) ? 0x3F80u : 0u) | (((k0 + 1 == m) ? 0x3F80u : 0u) << 16);
        int k2 = 16 + h * 8 + 2 * r;
        unsigned hi2 = ((k2 == m) ? 0x3F80u : 0u) | (((k2 + 1 == m) ? 0x3F80u : 0u) << 16);
        B0X.u[r] = lo;  B1X.u[r] = hi2;
        B0Y.u[r] = lo;  B1Y.u[r] = hi2;
    }

    const float* fb = feats + (size_t)item * NS * NTAG;
    const int*   lb = labels + (size_t)item * NS;

    f32x16 zc;
    #pragma unroll
    for (int e = 0; e < 16; ++e) zc[e] = 0.0f;

    f32x16 CX, CY;
    int cregX = 0, kpX = 0, cregY = 0, kpY = 0;

    // One matmul step: C_ = A(EX) * B_, then relayout C_ -> B_ (verified R6-R8)
    #define P1_STEP1(C_, B0_, B1_, EX)                                           \
    {                                                                            \
        f32x2 ex2; ex2.x = (EX); ex2.y = (EX);                                   \
        PKU A0, A1;                                                              \
        _Pragma("unroll")                                                        \
        for (int r = 0; r < 4; ++r) {                                            \
            f32x2 p0 = ex2 * Efrag2[r];                                          \
            f32x2 p1 = ex2 * Efrag2[4 + r];                                      \
            A0.u[r] = pk2(p0.x, p0.y);                                           \
            A1.u[r] = pk2(p1.x, p1.y);                                           \
        }                                                                        \
        C_ = __builtin_amdgcn_mfma_f32_32x32x16_bf16(A0.v, B0_.v, zc, 0, 0, 0);  \
        C_ = __builtin_amdgcn_mfma_f32_32x32x16_bf16(A1.v, B1_.v, C_, 0, 0, 0);  \
        unsigned P01 = pk2(C_[0],  C_[1]);                                       \
        unsigned P23 = pk2(C_[2],  C_[3]);                                       \
        unsigned P45 = pk2(C_[4],  C_[5]);                                       \
        unsigned P67 = pk2(C_[6],  C_[7]);                                       \
        unsigned Q01 = pk2(C_[8],  C_[9]);                                       \
        unsigned Q23 = pk2(C_[10], C_[11]);                                      \
        unsigned Q45 = pk2(C_[12], C_[13]);                                      \
        unsigned Q67 = pk2(C_[14], C_[15]);                                      \
        u32x2 r0 = __builtin_amdgcn_permlane32_swap(P01, P45, false, false);     \
        u32x2 r1 = __builtin_amdgcn_permlane32_swap(P23, P67, false, false);     \
        u32x2 r2 = __builtin_amdgcn_permlane32_swap(Q01, Q45, false, false);     \
        u32x2 r3 = __builtin_amdgcn_permlane32_swap(Q23, Q67, false, false);     \
        B0_.u[0] = r0.x; B0_.u[2] = r0.y;                                        \
        B0_.u[1] = r1.x; B0_.u[3] = r1.y;                                        \
        B1_.u[0] = r2.x; B1_.u[2] = r2.y;                                        \
        B1_.u[1] = r3.x; B1_.u[3] = r3.y;                                        \
    }
    #define EXPO_OF(C_) (min(max((__builtin_amdgcn_readfirstlane(               \
        __float_as_int(C_[0])) >> 23) & 0xFF, 1), 254) - 127)

    const int tbX = 1 + startX, tbY = 1 + startY;
    #define IDXX(X) ((size_t)min(tbX + (X), NS - 1) * NTAG + m)
    #define IDXY(X) ((size_t)min(tbY + (X), NS - 1) * NTAG + m)

    // prefetch 2 iterations (8 steps) per chain
    float fX0 = fb[IDXX(0)], fX1 = fb[IDXX(1)], fX2 = fb[IDXX(2)], fX3 = fb[IDXX(3)];
    float fX4 = fb[IDXX(4)], fX5 = fb[IDXX(5)], fX6 = fb[IDXX(6)], fX7 = fb[IDXX(7)];
    float fY0 = fb[IDXY(0)], fY1 = fb[IDXY(1)], fY2 = fb[IDXY(2)], fY3 = fb[IDXY(3)];
    float fY4 = fb[IDXY(4)], fY5 = fb[IDXY(5)], fY6 = fb[IDXY(6)], fY7 = fb[IDXY(7)];

    const int nf = cntY >> 2;   // full 4-step iterations for both chains
    for (int it = 0; it < nf; ++it) {
        const int s8 = 4 * it + 8;
        float nX0 = fb[IDXX(s8 + 0)], nX1 = fb[IDXX(s8 + 1)];
        float nX2 = fb[IDXX(s8 + 2)], nX3 = fb[IDXX(s8 + 3)];
        float nY0 = fb[IDXY(s8 + 0)], nY1 = fb[IDXY(s8 + 1)];
        float nY2 = fb[IDXY(s8 + 2)], nY3 = fb[IDXY(s8 + 3)];

        // per-iteration scale factors, all off the MFMA chain
        cregX += kpX;  cregY += kpY;
        float eX0 = fexp2(fmaf(fX0, LOG2E, -(float)kpX));
        float eX1 = fexp2(fX1 * LOG2E);
        float eX2 = fexp2(fX2 * LOG2E);
        float eX3 = fexp2(fX3 * LOG2E);
        float eY0 = fexp2(fmaf(fY0, LOG2E, -(float)kpY));
        float eY1 = fexp2(fY1 * LOG2E);
        float eY2 = fexp2(fY2 * LOG2E);
        float eY3 = fexp2(fY3 * LOG2E);

        P1_STEP1(CX, B0X, B1X, eX0)
        P1_STEP1(CY, B0Y, B1Y, eY0)
        kpX = EXPO_OF(CX);          // 3-step-stale renorm capture
        kpY = EXPO_OF(CY);
        P1_STEP1(CX, B0X, B1X, eX1)
        P1_STEP1(CY, B0Y, B1Y, eY1)
        P1_STEP1(CX, B0X, B1X, eX2)
        P1_STEP1(CY, B0Y, B1Y, eY2)
        P1_STEP1(CX, B0X, B1X, eX3)
        P1_STEP1(CY, B0Y, B1Y, eY3)

        fX0 = fX4; fX1 = fX5; fX2 = fX6; fX3 = fX7;
        fX4 = nX0; fX5 = nX1; fX6 = nX2; fX7 = nX3;
        fY0 = fY4; fY1 = fY5; fY2 = fY6; fY3 = fY7;
        fY4 = nY0; fY5 = nY1; fY6 = nY2; fY7 = nY3;
    }

    // remainders (<=4 steps each; first remainder step applies pending scale)
    const int remX = cntX - 4 * nf;
    const int remY = cntY - 4 * nf;
    if (remX >= 1) { cregX += kpX;
                     float e0 = fexp2(fmaf(fX0, LOG2E, -(float)kpX));
                     P1_STEP1(CX, B0X, B1X, e0) }
    if (remX >= 2) { float e1 = fexp2(fX1 * LOG2E); P1_STEP1(CX, B0X, B1X, e1) }
    if (remX >= 3) { float e2 = fexp2(fX2 * LOG2E); P1_STEP1(CX, B0X, B1X, e2) }
    if (remX >= 4) { float e3 = fexp2(fX3 * LOG2E); P1_STEP1(CX, B0X, B1X, e3) }
    if (remY >= 1) { cregY += kpY;
                     float e0 = fexp2(fmaf(fY0, LOG2E, -(float)kpY));
                     P1_STEP1(CY, B0Y, B1Y, e0) }
    if (remY >= 2) { float e1 = fexp2(fY1 * LOG2E); P1_STEP1(CY, B0Y, B1Y, e1) }
    if (remY >= 3) { float e2 = fexp2(fY2 * LOG2E); P1_STEP1(CY, B0Y, B1Y, e2) }
    #undef P1_STEP1
    #undef EXPO_OF
    #undef IDXX
    #undef IDXY

    // store chunk matrices (identity if empty)
    unsigned short* outX = wsM + ((size_t)(item * NCHUNK + cX) << 10);
    unsigned short* outY = wsM + ((size_t)(item * NCHUNK + cY) << 10);
    #pragma unroll
    for (int s = 0; s < 16; ++s) {
        int rowm = (s & 3) + 8 * (s >> 2) + 4 * h;
        unsigned short idv = (rowm == m) ? (unsigned short)0x3F80 : (unsigned short)0;
        unsigned short vx = (cntX > 0) ? (unsigned short)(pk2(CX[s], 0.0f) & 0xFFFFu) : idv;
        unsigned short vy = (cntY > 0) ? (unsigned short)(pk2(CY[s], 0.0f) & 0xFFFFu) : idv;
        outX[s * 64 + lane] = vx;
        outY[s * 64 + lane] = vy;
    }
    if (lane == 0) {
        wsK[item * NCHUNK + cX] = cregX;
        wsK[item * NCHUNK + cY] = cregY;
    }

    // ---- gold score for this item (parallel gather over 256 threads) ----
    float gold = 0.0f;
    #pragma unroll
    for (int k = 0; k < 2; ++k) {
        int tt = (k << 8) + tid;
        if (tt < len) {
            int lab_t = lb[tt];
            gold += fb[(size_t)tt * NTAG + lab_t];
            if (tt > 0)
                gold += trans[(lb[tt - 1] << 5) + lab_t];
            else
                gold += trans[(TSTART << 5) + lab_t];
            if (tt == len - 1)
                gold += trans[(lab_t << 5) + TSTOP];
        }
    }
    #pragma unroll
    for (int mm = 1; mm <= 32; mm <<= 1)
        gold += __shfl_xor(gold, mm, 64);
    if (lane == 0) s_g[wid] = gold;
    __syncthreads();
    if (tid == 0)
        atomicAdd(out, -(s_g[0] + s_g[1] + s_g[2] + s_g[3]) * (1.0f / 1024.0f));
}

// ---------------- Phase 2: combine + forward score ----------------
__global__ __launch_bounds__(64)
void crf_phase2(const float* __restrict__ feats,
                const int*   __restrict__ lengths,
                const float* __restrict__ trans,
                const unsigned short* __restrict__ wsM,
                const int*            __restrict__ wsK,
                float* __restrict__ out)
{
    __shared__ float s_p[32];
    const int j   = threadIdx.x;
    const int j32 = j & 31;
    const int b   = blockIdx.x;

    const float* fb = feats + (size_t)b * NS * NTAG;

    float p = fexp2((fb[j32] + trans[(TSTART << 5) + j32]) * LOG2E);

    // all renorm counters summed upfront (order-independent)
    int cacc = 0;
    {
        const int4* kp = (const int4*)(wsK + b * NCHUNK);
        int4 k0 = kp[0], k1 = kp[1];
        cacc = k0.x + k0.y + k0.z + k0.w + k1.x + k1.y + k1.z + k1.w;
    }

    const int s  = (j32 & 3) | (((j32 >> 3) & 3) << 2);
    const int hh = (j32 >> 2) & 1;
    const unsigned short* Mb = wsM + ((size_t)(b * NCHUNK) << 10);

    uint4 cur[4];
    {
        const uint4* rp = (const uint4*)(Mb + s * 64 + hh * 32);
        cur[0] = rp[0]; cur[1] = rp[1]; cur[2] = rp[2]; cur[3] = rp[3];
    }

    for (int c = 0; c < NCHUNK; ++c) {
        uint4 nxt[4];
        if (c + 1 < NCHUNK) {
            const uint4* rp = (const uint4*)(Mb + ((size_t)(c + 1) << 10) + s * 64 + hh * 32);
            nxt[0] = rp[0]; nxt[1] = rp[1]; nxt[2] = rp[2]; nxt[3] = rp[3];
        }

        __syncthreads();
        s_p[j32] = p;
        __syncthreads();

        const unsigned short* rw = (const unsigned short*)cur;
        float q0 = 0.f, q1 = 0.f, q2 = 0.f, q3 = 0.f;
        #pragma unroll
        for (int n = 0; n < 32; n += 4) {
            q0 = fmaf(__uint_as_float(((unsigned)rw[n + 0]) << 16), s_p[n + 0], q0);
            q1 = fmaf(__uint_as_float(((unsigned)rw[n + 1]) << 16), s_p[n + 1], q1);
            q2 = fmaf(__uint_as_float(((unsigned)rw[n + 2]) << 16), s_p[n + 2], q2);
            q3 = fmaf(__uint_as_float(((unsigned)rw[n + 3]) << 16), s_p[n + 3], q3);
        }
        float q = (q0 + q1) + (q2 + q3);

        int bits = __builtin_amdgcn_readfirstlane(__float_as_int(q));
        int e_ = min(max((bits >> 23) & 0xFF, 1), 254);
        cacc += e_ - 127;
        p = q * __uint_as_float((unsigned)(254 - e_) << 23);   // q * 2^-k

        cur[0] = nxt[0]; cur[1] = nxt[1]; cur[2] = nxt[2]; cur[3] = nxt[3];
    }

    float ssum = p;
    #pragma unroll
    for (int mm = 1; mm <= 16; mm <<= 1)
        ssum += __shfl_xor(ssum, mm, 64);
    float fwd = (float)cacc * LN2 + logf(ssum);

    if (j == 0)
        atomicAdd(out, fwd * (1.0f / 1024.0f));
}

extern "C" void kernel_launch(void* const* d_in, const int* in_sizes, int n_in,
                              void* d_out, int out_size, void* d_ws, size_t ws_size,
                              hipStream_t stream) {
    const float* feats   = (const float*)d_in[0];
    const int*   labels  = (const int*)d_in[1];
    const int*   lengths = (const int*)d_in[2];
    const float* trans   = (const float*)d_in[3];
    float*       out     = (float*)d_out;

    unsigned short* wsM = (unsigned short*)d_ws;                 // 16 MiB
    int*            wsK = (int*)((char*)d_ws + (size_t)NB * NCHUNK * 1024 * 2);

    hipMemsetAsync(out, 0, sizeof(float) * (size_t)out_size, stream);
    crf_phase1<<<dim3(NB), dim3(256), 0, stream>>>(feats, labels, lengths, trans, wsM, wsK, out);
    crf_phase2<<<dim3(NB), dim3(64), 0, stream>>>(feats, lengths, trans, wsM, wsK, out);
}